// Round 1
// 211.193 us; speedup vs baseline: 1.4272x; 1.4272x over previous
//
#include <hip/hip_runtime.h>

// ---------------- problem constants ----------------
#define BATCH   4096
#define N_REL   500
#define D1      200
#define W_IN    400          // 2*D1
#define OC      32
#define FW      9
#define W_OUT   392          // W_IN - FW + 1
#define FC_LEN  12544        // OC * W_OUT
#define FC1_LEN 288          // OC * FW
#define EPS     1e-5f

#define OSPLIT  8            // o-dim split for wbig GEMV
#define OCH     50           // 400 / OSPLIT
#define WBLK    49           // 12544 / 256

// ============================================================================
// Algebraic collapse: fc2_w is [1,400] -> the entire post-conv network is an
// affine map into ONE scalar per example.
//   pre[b] = s0 * ( E[i1]·P[rel,0:200] + E[i2]·P[rel,200:400] ) + crel[rel]
//   out[b] = tanh(pre[b]) + bias
// where
//   wbig[k]   = sum_o fc_w[o,k] * s2[o]*fc2w[o]                  (GEMV, 20 MB)
//   kf        = (R·fc1w + fc1b) * inv1          (= existing krel output, 500 rels)
//   P[rel,d]  = sum_{oc,j} kf[rel,oc,j] * wbig[oc*392 + d - j]   (500x400)
//   crel[rel] = t0 * sum_d P[rel,d] + C1 + C2 + C3               (constants)
// ============================================================================

// ============ kernel A: per-relation hypernet filters, bn1 scale folded ====
// KR[rel][i] = (R[rel]·fc1_w[i] + fc1_b[i]) * inv1[i/9],  i < 288
__global__ __launch_bounds__(320)
void krel(const float* __restrict__ R, const float* __restrict__ fc1w,
          const float* __restrict__ fc1b,
          const float* __restrict__ g1, const float* __restrict__ v1,
          float* __restrict__ KR)
{
    __shared__ float rs[D1];
    const int rel = blockIdx.x;
    const int t = threadIdx.x;
    if (t < D1) rs[t] = R[(size_t)rel * D1 + t];
    __syncthreads();
    if (t < FC1_LEN) {
        const float4* wrow = (const float4*)(fc1w + (size_t)t * D1);
        float acc = fc1b[t];
        #pragma unroll 10
        for (int c = 0; c < D1 / 4; ++c) {
            float4 wv = wrow[c];
            acc += rs[c * 4 + 0] * wv.x + rs[c * 4 + 1] * wv.y
                 + rs[c * 4 + 2] * wv.z + rs[c * 4 + 3] * wv.w;
        }
        const int oc = t / FW;
        KR[(size_t)rel * FC1_LEN + t] = acc * (g1[oc] * rsqrtf(v1[oc] + EPS));
    }
}

// ============ kernel W1: wbig GEMV partials over o-slices ===================
// wpart[y][k] = sum_{o in y-th slice of 50} fc_w[o,k] * (s2[o]*fc2w[o])
__global__ __launch_bounds__(256)
void wpart_k(const float* __restrict__ fcw, const float* __restrict__ g2,
             const float* __restrict__ v2, const float* __restrict__ fc2w,
             float* __restrict__ wpart)
{
    __shared__ float wts[OCH];
    const int t = threadIdx.x;
    const int k = blockIdx.x * 256 + t;
    const int o0 = blockIdx.y * OCH;
    if (t < OCH) {
        const int o = o0 + t;
        wts[t] = fc2w[o] * g2[o] * rsqrtf(v2[o] + EPS);
    }
    __syncthreads();
    float acc = 0.f;
    #pragma unroll 10
    for (int i = 0; i < OCH; ++i)
        acc += fcw[(size_t)(o0 + i) * FC_LEN + k] * wts[i];
    wpart[blockIdx.y * FC_LEN + k] = acc;
}

// ============ kernel W2: combine partials -> wbig; constant partials ========
// c3part[bx] = sum over this block's k of cb1[k/392]*wbig[k]
//              (+ block 0 adds C1+C2+fc2b terms)
__global__ __launch_bounds__(256)
void wsum_k(const float* __restrict__ wpart,
            const float* __restrict__ g1, const float* __restrict__ b1,
            const float* __restrict__ m1, const float* __restrict__ v1,
            const float* __restrict__ g2, const float* __restrict__ b2,
            const float* __restrict__ m2, const float* __restrict__ v2,
            const float* __restrict__ fcb, const float* __restrict__ fc2w,
            const float* __restrict__ fc2b,
            float* __restrict__ wbig, float* __restrict__ c3part)
{
    __shared__ float red[256];
    const int t = threadIdx.x;
    const int k = blockIdx.x * 256 + t;
    float w8 = 0.f;
    #pragma unroll
    for (int y = 0; y < OSPLIT; ++y) w8 += wpart[y * FC_LEN + k];
    wbig[k] = w8;
    const int oc = k / W_OUT;
    const float inv1 = g1[oc] * rsqrtf(v1[oc] + EPS);
    float pc = (b1[oc] - m1[oc] * inv1) * w8;
    if (blockIdx.x == 0) {
        for (int o = t; o < W_IN; o += 256) {
            const float s2 = g2[o] * rsqrtf(v2[o] + EPS);
            pc += (b2[o] - m2[o] * s2 + fcb[o] * s2) * fc2w[o];
        }
        if (t == 0) pc += fc2b[0];
    }
    red[t] = pc;
    __syncthreads();
    #pragma unroll
    for (int s = 128; s > 0; s >>= 1) {
        if (t < s) red[t] += red[t + s];
        __syncthreads();
    }
    if (t == 0) c3part[blockIdx.x] = red[0];
}

// ============ kernel P: per-relation score vector (s0 folded) + crel ========
// P[rel,d]   = sum_{oc} sum_{j=jlo(d)}^{jhi(d)} KR[rel,oc*9+j]*wbig[oc*392+d-j]
// Ps[rel,d]  = s0 * P[rel,d]
// crel[rel]  = t0 * sum_d P[rel,d] + sum(c3part)
__global__ __launch_bounds__(256)
void prel_k(const float* __restrict__ KR, const float* __restrict__ wbig,
            const float* __restrict__ c3part,
            const float* __restrict__ g0, const float* __restrict__ b0,
            const float* __restrict__ m0p, const float* __restrict__ v0,
            float* __restrict__ Ps, float* __restrict__ crel)
{
    __shared__ __align__(16) float wls[FC_LEN];   // 50176 B
    __shared__ float kfs[FC1_LEN];
    __shared__ float red[256];
    const int rel = blockIdx.x;
    const int t = threadIdx.x;

    for (int i = t; i < FC_LEN / 4; i += 256)
        *(float4*)(wls + i * 4) = *(const float4*)(wbig + i * 4);
    for (int i = t; i < FC1_LEN; i += 256)
        kfs[i] = KR[(size_t)rel * FC1_LEN + i];
    __syncthreads();

    const float s0 = g0[0] * rsqrtf(v0[0] + EPS);
    const float t0 = b0[0] - m0p[0] * s0;

    float lsum = 0.f;
    for (int d = t; d < W_IN; d += 256) {
        const int jlo = (d > W_OUT - 1) ? d - (W_OUT - 1) : 0;
        const int jhi = (d < FW - 1) ? d : (FW - 1);
        float p = 0.f;
        for (int oc = 0; oc < OC; ++oc) {
            const float* wb = wls + oc * W_OUT + d;
            const float* kk = kfs + oc * FW;
            for (int j = jlo; j <= jhi; ++j)
                p += kk[j] * wb[-j];
        }
        lsum += p;
        Ps[(size_t)rel * W_IN + d] = s0 * p;
    }
    red[t] = lsum;
    __syncthreads();
    #pragma unroll
    for (int s = 128; s > 0; s >>= 1) {
        if (t < s) red[t] += red[t + s];
        __syncthreads();
    }
    if (t == 0) {
        float cg = 0.f;
        for (int i = 0; i < WBLK; ++i) cg += c3part[i];
        crel[rel] = t0 * red[0] + cg;
    }
}

// ============ kernel F: per-example gather + dot(400) + tanh ================
__global__ __launch_bounds__(256)
void final_k(const int* __restrict__ e1i, const int* __restrict__ ri,
             const int* __restrict__ e2i,
             const float* __restrict__ E, const float* __restrict__ Ps,
             const float* __restrict__ crel, const float* __restrict__ bias,
             float* __restrict__ out)
{
    const int wave = threadIdx.x >> 6, lane = threadIdx.x & 63;
    const int e = blockIdx.x * 4 + wave;
    const int i1 = e1i[e], i2 = e2i[e], rel = ri[e];
    const float* P  = Ps + (size_t)rel * W_IN;
    const float* E1 = E + (size_t)i1 * D1;
    const float* E2 = E + (size_t)i2 * D1;
    float acc = 0.f;
    for (int d = lane; d < D1; d += 64) acc += E1[d] * P[d];
    for (int d = lane; d < D1; d += 64) acc += E2[d] * P[D1 + d];
    #pragma unroll
    for (int off = 32; off > 0; off >>= 1) acc += __shfl_down(acc, off);
    if (lane == 0) out[e] = tanhf(acc + crel[rel]) + bias[0];
}

extern "C" void kernel_launch(void* const* d_in, const int* in_sizes, int n_in,
                              void* d_out, int out_size, void* d_ws, size_t ws_size,
                              hipStream_t stream)
{
    const int*   e1i  = (const int*)d_in[0];
    const int*   ri   = (const int*)d_in[1];
    const int*   e2i  = (const int*)d_in[2];
    const float* E    = (const float*)d_in[3];
    const float* R    = (const float*)d_in[4];
    const float* g0   = (const float*)d_in[5];
    const float* b0   = (const float*)d_in[6];
    const float* m0p  = (const float*)d_in[7];
    const float* v0   = (const float*)d_in[8];
    const float* fc1w = (const float*)d_in[9];
    const float* fc1b = (const float*)d_in[10];
    const float* g1   = (const float*)d_in[11];
    const float* b1   = (const float*)d_in[12];
    const float* m1   = (const float*)d_in[13];
    const float* v1   = (const float*)d_in[14];
    const float* fcw  = (const float*)d_in[15];
    const float* fcb  = (const float*)d_in[16];
    const float* g2   = (const float*)d_in[17];
    const float* b2   = (const float*)d_in[18];
    const float* m2   = (const float*)d_in[19];
    const float* v2   = (const float*)d_in[20];
    const float* fc2w = (const float*)d_in[21];
    const float* fc2b = (const float*)d_in[22];
    const float* bias = (const float*)d_in[23];

    // workspace layout (all 16B-aligned, ~1.8 MB total)
    char* ws = (char*)d_ws;
    float* KR     = (float*)(ws + 0);              //  576000 B
    float* wpart  = (float*)(ws + 576000);         //  401408 B
    float* wbig   = (float*)(ws + 977408);         //   50176 B
    float* c3part = (float*)(ws + 1027584);        //     196 B
    float* Ps     = (float*)(ws + 1027840);        //  800000 B
    float* crel   = (float*)(ws + 1827840);        //    2000 B  -> 1829840 total
    (void)ws_size; (void)in_sizes; (void)n_in; (void)out_size;

    krel<<<N_REL, 320, 0, stream>>>(R, fc1w, fc1b, g1, v1, KR);
    wpart_k<<<dim3(WBLK, OSPLIT), 256, 0, stream>>>(fcw, g2, v2, fc2w, wpart);
    wsum_k<<<WBLK, 256, 0, stream>>>(wpart, g1, b1, m1, v1, g2, b2, m2, v2,
                                     fcb, fc2w, fc2b, wbig, c3part);
    prel_k<<<N_REL, 256, 0, stream>>>(KR, wbig, c3part, g0, b0, m0p, v0, Ps, crel);
    final_k<<<BATCH / 4, 256, 0, stream>>>(e1i, ri, e2i, E, Ps, crel, bias,
                                           (float*)d_out);
}